// Round 1
// baseline (565.069 us; speedup 1.0000x reference)
//
#include <hip/hip_runtime.h>

#define EPSF 1e-6f

// N=8, L=S=4096, E=256, H=8, D=32. M = N*L = 32768 rows for all GEMMs.
// All GEMMs: Y[M,256] = f(X[M,256] @ W[256,256]^T + b)

// MODE 0: y = (elu(x)+1) * mask[row]   (bias, used for Qf / Kf)
// MODE 1: y = x * mask[row]            (bias, used for Vm = (v@Wv^T+bv)*km)
// MODE 2: y = x                        (no bias/mask, final merge GEMM)
template<int MODE>
__global__ __launch_bounds__(256) void gemm_ep(
    const float* __restrict__ X, const float* __restrict__ W,
    const float* __restrict__ bias, const int* __restrict__ mask,
    float* __restrict__ Y)
{
    constexpr int Kdim = 256;
    const int j0 = blockIdx.x * 64;   // output-column tile
    const int m0 = blockIdx.y * 64;   // row tile
    const int t  = threadIdx.x;

    __shared__ float Xs[16][68];      // [k][m], pad to 68 for 16B-aligned float4 reads
    __shared__ float Ws[16][68];      // [k][j]

    const int lr = t >> 2;            // 0..63 : tile row loaded
    const int lc = (t & 3) * 4;       // 0,4,8,12 : k-offset loaded (float4)
    const int tm = t >> 4;            // 0..15
    const int tn = t & 15;            // 0..15

    float acc[4][4] = {{0.f,0.f,0.f,0.f},{0.f,0.f,0.f,0.f},
                       {0.f,0.f,0.f,0.f},{0.f,0.f,0.f,0.f}};

    for (int k0 = 0; k0 < Kdim; k0 += 16) {
        float4 xa = *(const float4*)(X + (size_t)(m0 + lr) * Kdim + k0 + lc);
        float4 wa = *(const float4*)(W + (size_t)(j0 + lr) * Kdim + k0 + lc);
        Xs[lc+0][lr] = xa.x; Xs[lc+1][lr] = xa.y; Xs[lc+2][lr] = xa.z; Xs[lc+3][lr] = xa.w;
        Ws[lc+0][lr] = wa.x; Ws[lc+1][lr] = wa.y; Ws[lc+2][lr] = wa.z; Ws[lc+3][lr] = wa.w;
        __syncthreads();
        #pragma unroll
        for (int k = 0; k < 16; ++k) {
            float4 a = *(const float4*)&Xs[k][tm * 4];
            float4 b = *(const float4*)&Ws[k][tn * 4];
            acc[0][0] += a.x*b.x; acc[0][1] += a.x*b.y; acc[0][2] += a.x*b.z; acc[0][3] += a.x*b.w;
            acc[1][0] += a.y*b.x; acc[1][1] += a.y*b.y; acc[1][2] += a.y*b.z; acc[1][3] += a.y*b.w;
            acc[2][0] += a.z*b.x; acc[2][1] += a.z*b.y; acc[2][2] += a.z*b.z; acc[2][3] += a.z*b.w;
            acc[3][0] += a.w*b.x; acc[3][1] += a.w*b.y; acc[3][2] += a.w*b.z; acc[3][3] += a.w*b.w;
        }
        __syncthreads();
    }

    float4 bb = {0.f, 0.f, 0.f, 0.f};
    if (MODE != 2) bb = *(const float4*)(bias + j0 + tn * 4);

    #pragma unroll
    for (int i = 0; i < 4; ++i) {
        const int row = m0 + tm * 4 + i;
        float mv = 1.f;
        if (MODE != 2) mv = mask[row] ? 1.f : 0.f;
        float4 o;
        float v0 = acc[i][0], v1 = acc[i][1], v2 = acc[i][2], v3 = acc[i][3];
        if (MODE != 2) { v0 += bb.x; v1 += bb.y; v2 += bb.z; v3 += bb.w; }
        if (MODE == 0) {
            v0 = (v0 > 0.f) ? (v0 + 1.f) : __expf(v0);
            v1 = (v1 > 0.f) ? (v1 + 1.f) : __expf(v1);
            v2 = (v2 > 0.f) ? (v2 + 1.f) : __expf(v2);
            v3 = (v3 > 0.f) ? (v3 + 1.f) : __expf(v3);
        }
        o.x = v0 * mv; o.y = v1 * mv; o.z = v2 * mv; o.w = v3 * mv;
        *(float4*)(Y + (size_t)row * 256 + j0 + tn * 4) = o;
    }
}

// KV'[n,h,d,v] = sum_s Kf[n,s,h,d] * Vm[n,s,h,v]; Ksum[n,h,d] = sum_s Kf[n,s,h,d]
// One block per (n,h): 64 blocks, 256 threads.
__global__ __launch_bounds__(256) void kv_agg(
    const float* __restrict__ Kf, const float* __restrict__ Vm,
    float* __restrict__ KV, float* __restrict__ Ksum)
{
    const int blk = blockIdx.x;          // n*8 + h
    const int n = blk >> 3, h = blk & 7;
    const int t = threadIdx.x;

    __shared__ float Ks[64][32];
    __shared__ float Vs[64][32];

    const int d  = t >> 3;               // 0..31
    const int v0 = (t & 7) * 4;          // 0..28
    const int lr = t >> 3;               // load row 0..31 (and +32)
    const int lc = (t & 7) * 4;          // load col

    float a0 = 0.f, a1 = 0.f, a2 = 0.f, a3 = 0.f, ks = 0.f;
    const size_t base = ((size_t)n * 4096) * 256 + h * 32;

    for (int s0 = 0; s0 < 4096; s0 += 64) {
        const float* kp = Kf + base + (size_t)s0 * 256;
        const float* vp = Vm + base + (size_t)s0 * 256;
        *(float4*)&Ks[lr][lc]      = *(const float4*)(kp + (size_t)lr * 256 + lc);
        *(float4*)&Ks[lr + 32][lc] = *(const float4*)(kp + (size_t)(lr + 32) * 256 + lc);
        *(float4*)&Vs[lr][lc]      = *(const float4*)(vp + (size_t)lr * 256 + lc);
        *(float4*)&Vs[lr + 32][lc] = *(const float4*)(vp + (size_t)(lr + 32) * 256 + lc);
        __syncthreads();
        #pragma unroll
        for (int s = 0; s < 64; ++s) {
            float kd = Ks[s][d];
            a0 += kd * Vs[s][v0 + 0];
            a1 += kd * Vs[s][v0 + 1];
            a2 += kd * Vs[s][v0 + 2];
            a3 += kd * Vs[s][v0 + 3];
            ks += kd;
        }
        __syncthreads();
    }
    float* kvp = KV + (size_t)blk * 1024 + d * 32 + v0;
    kvp[0] = a0; kvp[1] = a1; kvp[2] = a2; kvp[3] = a3;
    if ((t & 7) == 0) Ksum[blk * 32 + d] = ks;
}

// out[n,l,h,v] = (sum_d Qf*KV') / (sum_d Qf*Ksum + EPS)
// Grid (64, 8): block = (l-tile of 64, n). 256 threads = 256 output columns.
__global__ __launch_bounds__(256) void attn_out(
    const float* __restrict__ Qf, const float* __restrict__ KV,
    const float* __restrict__ Ksum, float* __restrict__ Out)
{
    const int n  = blockIdx.y;
    const int l0 = blockIdx.x * 64;
    const int t  = threadIdx.x;

    __shared__ float KVs[8 * 1024];
    __shared__ float KSs[8 * 32];

    const float4* kvsrc = (const float4*)(KV + (size_t)n * 8192);
    #pragma unroll
    for (int i = 0; i < 8; ++i)
        ((float4*)KVs)[t + i * 256] = kvsrc[t + i * 256];
    if (t < 64) ((float4*)KSs)[t] = ((const float4*)(Ksum + n * 256))[t];
    __syncthreads();

    const int c = t;                 // output column = h*32 + v
    const int h = c >> 5, v = c & 31;
    const float* kvh = &KVs[h * 1024];
    const float* ksh = &KSs[h * 32];

    for (int r = 0; r < 64; ++r) {
        const size_t row = (size_t)n * 4096 + l0 + r;
        const float* qf = Qf + row * 256 + h * 32;
        float num = 0.f, den = 0.f;
        #pragma unroll
        for (int d = 0; d < 32; ++d) {
            float q = qf[d];
            num += q * kvh[d * 32 + v];
            den += q * ksh[d];
        }
        Out[row * 256 + c] = num / (den + EPSF);
    }
}

extern "C" void kernel_launch(void* const* d_in, const int* in_sizes, int n_in,
                              void* d_out, int out_size, void* d_ws, size_t ws_size,
                              hipStream_t stream) {
    const float* q      = (const float*)d_in[0];
    const float* k      = (const float*)d_in[1];
    const float* v      = (const float*)d_in[2];
    const int*   q_mask = (const int*)  d_in[3];
    const int*   kv_mask= (const int*)  d_in[4];
    const float* Wq     = (const float*)d_in[5];
    const float* bq     = (const float*)d_in[6];
    const float* Wk     = (const float*)d_in[7];
    const float* bk     = (const float*)d_in[8];
    const float* Wv     = (const float*)d_in[9];
    const float* bv     = (const float*)d_in[10];
    const float* Wm     = (const float*)d_in[11];

    char* ws = (char*)d_ws;
    const size_t SZ = (size_t)8 * 4096 * 256 * sizeof(float);   // 33.55 MB
    float* Qf   = (float*)(ws);
    float* Kf   = (float*)(ws + SZ);
    float* Vm   = (float*)(ws + 2 * SZ);
    float* KVb  = (float*)(ws + 3 * SZ);                        // 64*1024 floats
    float* Ksum = (float*)(ws + 3 * SZ + 64 * 1024 * sizeof(float));
    float* Out  = Kf;   // reuse: Kf dead after kv_agg (stream-ordered)

    dim3 gblk(256);
    dim3 ggrid(4, 512);  // 256/64 col tiles, 32768/64 row tiles

    gemm_ep<0><<<ggrid, gblk, 0, stream>>>(q, Wq, bq, q_mask,  Qf);
    gemm_ep<0><<<ggrid, gblk, 0, stream>>>(k, Wk, bk, kv_mask, Kf);
    gemm_ep<1><<<ggrid, gblk, 0, stream>>>(v, Wv, bv, kv_mask, Vm);
    kv_agg  <<<dim3(64), gblk, 0, stream>>>(Kf, Vm, KVb, Ksum);
    attn_out<<<dim3(64, 8), gblk, 0, stream>>>(Qf, KVb, Ksum, Out);
    gemm_ep<2><<<ggrid, gblk, 0, stream>>>(Out, Wm, nullptr, nullptr, (float*)d_out);
}

// Round 2
// 260.330 us; speedup vs baseline: 2.1706x; 2.1706x over previous
//
#include <hip/hip_runtime.h>

#define EPSF 1e-6f

typedef __bf16 bf16;
typedef bf16 bf16x4 __attribute__((ext_vector_type(4)));
typedef bf16 bf16x8 __attribute__((ext_vector_type(8)));
typedef float f32x4 __attribute__((ext_vector_type(4)));

// ---------------------------------------------------------------------------
// GEMM: Y[M,256] = f(X[M,256] @ W[256,256]^T + b),  M = 32768
// MODE 0: y = (elu(x)+1)*mask[row]  (TIN=float, TOUT=bf16)   Qf/Kf
// MODE 1: y = x*mask[row]           (TIN=float, TOUT=bf16)   Vm
// MODE 2: y = x                     (TIN=bf16,  TOUT=float)  merge
// 128x128 tile, 4 waves (2x2), each wave 64x64 via 4x4 of 16x16x32 MFMA.
// ---------------------------------------------------------------------------
template<int MODE, typename TIN, typename TOUT>
__global__ __launch_bounds__(256) void gemm_ep(
    const TIN* __restrict__ X, const float* __restrict__ W,
    const float* __restrict__ bias, const int* __restrict__ mask,
    TOUT* __restrict__ Y)
{
    const int j0 = blockIdx.x * 128;   // output-column tile
    const int m0 = blockIdx.y * 128;   // row tile
    const int t  = threadIdx.x;
    const int lane = t & 63;
    const int w  = t >> 6;
    const int wm = (w >> 1) * 64;      // wave row offset in tile
    const int wn = (w & 1) * 64;       // wave col offset in tile

    // LDS row padded 32->40 bf16 (80B): m*20 mod 32 spreads banks, 2-way max (free)
    __shared__ bf16 As[128 * 40];
    __shared__ bf16 Bs[128 * 40];

    f32x4 acc[4][4] = {};

    for (int k0 = 0; k0 < 256; k0 += 32) {
        // stage W tile (always fp32 -> bf16)
        {
            const int br = t >> 3, bk = (t & 7) * 4;
            #pragma unroll
            for (int i = 0; i < 4; ++i) {
                const int row = br + 32 * i;
                float4 wv = *(const float4*)(W + (size_t)(j0 + row) * 256 + k0 + bk);
                bf16x4 p = { (bf16)wv.x, (bf16)wv.y, (bf16)wv.z, (bf16)wv.w };
                *(bf16x4*)&Bs[row * 40 + bk] = p;
            }
        }
        // stage X tile
        if constexpr (sizeof(TIN) == 4) {
            const int ar = t >> 3, ak = (t & 7) * 4;
            #pragma unroll
            for (int i = 0; i < 4; ++i) {
                const int row = ar + 32 * i;
                float4 xv = *(const float4*)(X + (size_t)(m0 + row) * 256 + k0 + ak);
                bf16x4 p = { (bf16)xv.x, (bf16)xv.y, (bf16)xv.z, (bf16)xv.w };
                *(bf16x4*)&As[row * 40 + ak] = p;
            }
        } else {
            const int ar = t >> 2, ak = (t & 3) * 8;
            #pragma unroll
            for (int i = 0; i < 2; ++i) {
                const int row = ar + 64 * i;
                *(bf16x8*)&As[row * 40 + ak] =
                    *(const bf16x8*)(X + (size_t)(m0 + row) * 256 + k0 + ak);
            }
        }
        __syncthreads();

        bf16x8 a[4], b[4];
        #pragma unroll
        for (int i = 0; i < 4; ++i) {
            a[i] = *(const bf16x8*)&As[(wm + i * 16 + (lane & 15)) * 40 + (lane >> 4) * 8];
            b[i] = *(const bf16x8*)&Bs[(wn + i * 16 + (lane & 15)) * 40 + (lane >> 4) * 8];
        }
        #pragma unroll
        for (int mi = 0; mi < 4; ++mi)
            #pragma unroll
            for (int ni = 0; ni < 4; ++ni)
                acc[mi][ni] = __builtin_amdgcn_mfma_f32_16x16x32_bf16(
                    a[mi], b[ni], acc[mi][ni], 0, 0, 0);
        __syncthreads();
    }

    // epilogue: C/D layout col = lane&15, row = (lane>>4)*4 + reg
    #pragma unroll
    for (int ni = 0; ni < 4; ++ni) {
        const int col = j0 + wn + ni * 16 + (lane & 15);
        const float bv = (MODE != 2) ? bias[col] : 0.f;
        #pragma unroll
        for (int mi = 0; mi < 4; ++mi) {
            const int rbase = m0 + wm + mi * 16 + (lane >> 4) * 4;
            #pragma unroll
            for (int r = 0; r < 4; ++r) {
                const int row = rbase + r;
                float x = acc[mi][ni][r];
                if (MODE != 2) x += bv;
                if (MODE == 0) x = (x > 0.f) ? (x + 1.f) : __expf(x);
                if (MODE != 2) x *= (mask[row] ? 1.f : 0.f);
                Y[(size_t)row * 256 + col] = (TOUT)x;
            }
        }
    }
}

// ---------------------------------------------------------------------------
// zero-init KV/Ksum accumulators (ws is poisoned 0xAA before every launch)
// ---------------------------------------------------------------------------
__global__ __launch_bounds__(256) void zero_f(float4* __restrict__ p, int n4) {
    const int i = blockIdx.x * 256 + threadIdx.x;
    if (i < n4) p[i] = float4{0.f, 0.f, 0.f, 0.f};
}

// ---------------------------------------------------------------------------
// KV'[nh,d,v] += sum_{s in chunk} Kf[n,s,h,d]*Vm[n,s,h,v]; Ksum[nh,d] += ...
// grid = 64 (n,h) * 16 S-chunks = 1024 blocks, 256 threads.
// ---------------------------------------------------------------------------
__global__ __launch_bounds__(256) void kv_agg(
    const bf16* __restrict__ Kf, const bf16* __restrict__ Vm,
    float* __restrict__ KV, float* __restrict__ Ksum)
{
    const int blk   = blockIdx.x;
    const int chunk = blk & 15;
    const int nh    = blk >> 4;
    const int n = nh >> 3, h = nh & 7;
    const int t = threadIdx.x;

    __shared__ float Ks[64][36];   // pad 32->36: conflict-light
    __shared__ float Vs[64][36];

    const int d  = t >> 3;          // 0..31
    const int v0 = (t & 7) * 4;     // 0..28
    const int lr = t >> 2;          // 0..63
    const int lk = (t & 3) * 8;     // 0..24

    float a0 = 0.f, a1 = 0.f, a2 = 0.f, a3 = 0.f, ks = 0.f;
    const size_t base = ((size_t)n * 4096 + chunk * 256) * 256 + h * 32;

    for (int s0 = 0; s0 < 256; s0 += 64) {
        bf16x8 kv8 = *(const bf16x8*)(Kf + base + (size_t)(s0 + lr) * 256 + lk);
        bf16x8 vv8 = *(const bf16x8*)(Vm + base + (size_t)(s0 + lr) * 256 + lk);
        float4 kf0 = {(float)kv8[0], (float)kv8[1], (float)kv8[2], (float)kv8[3]};
        float4 kf1 = {(float)kv8[4], (float)kv8[5], (float)kv8[6], (float)kv8[7]};
        float4 vf0 = {(float)vv8[0], (float)vv8[1], (float)vv8[2], (float)vv8[3]};
        float4 vf1 = {(float)vv8[4], (float)vv8[5], (float)vv8[6], (float)vv8[7]};
        *(float4*)&Ks[lr][lk]     = kf0;  *(float4*)&Ks[lr][lk + 4] = kf1;
        *(float4*)&Vs[lr][lk]     = vf0;  *(float4*)&Vs[lr][lk + 4] = vf1;
        __syncthreads();
        #pragma unroll
        for (int s = 0; s < 64; ++s) {
            const float kd = Ks[s][d];
            a0 += kd * Vs[s][v0 + 0];
            a1 += kd * Vs[s][v0 + 1];
            a2 += kd * Vs[s][v0 + 2];
            a3 += kd * Vs[s][v0 + 3];
            ks += kd;
        }
        __syncthreads();
    }
    float* kvp = KV + (size_t)nh * 1024 + d * 32 + v0;
    atomicAdd(kvp + 0, a0); atomicAdd(kvp + 1, a1);
    atomicAdd(kvp + 2, a2); atomicAdd(kvp + 3, a3);
    if ((t & 7) == 0) atomicAdd(Ksum + nh * 32 + d, ks);
}

// ---------------------------------------------------------------------------
// out[n,l,h,v] = (sum_d Qf*KV') / (sum_d Qf*Ksum + EPS), bf16 out
// grid (64, 8): 64-row l-tile, batch n. 256 threads = 256 output cols.
// ---------------------------------------------------------------------------
__global__ __launch_bounds__(256) void attn_out(
    const bf16* __restrict__ Qf, const float* __restrict__ KV,
    const float* __restrict__ Ksum, bf16* __restrict__ Out)
{
    const int n  = blockIdx.y;
    const int l0 = blockIdx.x * 64;
    const int t  = threadIdx.x;

    __shared__ float KVs[8 * 1024];
    __shared__ float KSs[8 * 32];
    __shared__ float Qs[8 * 260];   // pad 256->260

    const float4* kvsrc = (const float4*)(KV + (size_t)n * 8192);
    #pragma unroll
    for (int i = 0; i < 8; ++i)
        ((float4*)KVs)[t + i * 256] = kvsrc[t + i * 256];
    if (t < 64) ((float4*)KSs)[t] = ((const float4*)(Ksum + n * 256))[t];

    const int h = t >> 5, v = t & 31;
    const float* kvh = &KVs[h * 1024];
    const float* ksh = &KSs[h * 32];

    const int qr   = t >> 5;   // 0..7: row staged by this thread
    const int qseg = t & 31;   // 8-elem segment

    for (int r0 = 0; r0 < 64; r0 += 8) {
        __syncthreads();   // Qs reuse-protect (and KVs ready on first iter)
        bf16x8 q8 = *(const bf16x8*)(Qf + ((size_t)n * 4096 + l0 + r0 + qr) * 256 + qseg * 8);
        float4 q0 = {(float)q8[0], (float)q8[1], (float)q8[2], (float)q8[3]};
        float4 q1 = {(float)q8[4], (float)q8[5], (float)q8[6], (float)q8[7]};
        *(float4*)&Qs[qr * 260 + qseg * 8]     = q0;
        *(float4*)&Qs[qr * 260 + qseg * 8 + 4] = q1;
        __syncthreads();
        #pragma unroll 2
        for (int rr = 0; rr < 8; ++rr) {
            const float* qrow = &Qs[rr * 260 + h * 32];
            float num = 0.f, den = 0.f;
            #pragma unroll
            for (int d = 0; d < 32; ++d) {
                const float qd = qrow[d];
                num += qd * kvh[d * 32 + v];
                den += qd * ksh[d];
            }
            const size_t row = (size_t)n * 4096 + l0 + r0 + rr;
            Out[row * 256 + t] = (bf16)(num / (den + EPSF));
        }
    }
}

extern "C" void kernel_launch(void* const* d_in, const int* in_sizes, int n_in,
                              void* d_out, int out_size, void* d_ws, size_t ws_size,
                              hipStream_t stream) {
    const float* q      = (const float*)d_in[0];
    const float* k      = (const float*)d_in[1];
    const float* v      = (const float*)d_in[2];
    const int*   q_mask = (const int*)  d_in[3];
    const int*   kv_mask= (const int*)  d_in[4];
    const float* Wq     = (const float*)d_in[5];
    const float* bq     = (const float*)d_in[6];
    const float* Wk     = (const float*)d_in[7];
    const float* bk     = (const float*)d_in[8];
    const float* Wv     = (const float*)d_in[9];
    const float* bv     = (const float*)d_in[10];
    const float* Wm     = (const float*)d_in[11];

    char* ws = (char*)d_ws;
    const size_t SZB = (size_t)8 * 4096 * 256 * sizeof(bf16);   // 16.78 MB
    bf16*  Qf   = (bf16*)(ws);
    bf16*  Kf   = (bf16*)(ws + SZB);
    bf16*  Vm   = (bf16*)(ws + 2 * SZB);
    bf16*  Out  = (bf16*)(ws + 3 * SZB);
    float* KVb  = (float*)(ws + 4 * SZB);                       // 64*1024 f32
    float* Ksum = (float*)(ws + 4 * SZB + 64 * 1024 * sizeof(float));

    const dim3 blk(256);
    const dim3 ggrid(2, 256);   // 256/128 col tiles, 32768/128 row tiles

    gemm_ep<0, float, bf16><<<ggrid, blk, 0, stream>>>(q, Wq, bq, q_mask,  Qf);
    gemm_ep<0, float, bf16><<<ggrid, blk, 0, stream>>>(k, Wk, bk, kv_mask, Kf);
    gemm_ep<1, float, bf16><<<ggrid, blk, 0, stream>>>(v, Wv, bv, kv_mask, Vm);

    const int n4 = (64 * 1024 + 64 * 32) / 4;   // KV + Ksum floats / 4
    zero_f<<<dim3((n4 + 255) / 256), blk, 0, stream>>>((float4*)KVb, n4);

    kv_agg  <<<dim3(1024),  blk, 0, stream>>>(Kf, Vm, KVb, Ksum);
    attn_out<<<dim3(64, 8), blk, 0, stream>>>(Qf, KVb, Ksum, Out);

    gemm_ep<2, bf16, float><<<ggrid, blk, 0, stream>>>(Out, Wm, nullptr, nullptr, (float*)d_out);
}

// Round 3
// 233.167 us; speedup vs baseline: 2.4234x; 1.1165x over previous
//
#include <hip/hip_runtime.h>

#define EPSF 1e-6f

typedef __bf16 bf16;
typedef bf16 bf16x4 __attribute__((ext_vector_type(4)));
typedef bf16 bf16x8 __attribute__((ext_vector_type(8)));
typedef float f32x4 __attribute__((ext_vector_type(4)));

// N=8, L=S=4096, E=256, H=8, D=32.
// ws layout: KV fp32 [64][32v][32d] (256KB) | Ksum fp32 [8][256] (8KB) | Wb bf16 x4 (512KB)

// ---------------------------------------------------------------------------
// prep: zero KV+Ksum (67584 floats = 16896 float4) and convert 4 W to bf16.
// grid 322 x 256: blocks 0..65 zero, 66..321 convert (4 matrices x 64 parts).
// ---------------------------------------------------------------------------
__global__ __launch_bounds__(256) void prep(
    const float* __restrict__ Wq, const float* __restrict__ Wk,
    const float* __restrict__ Wv, const float* __restrict__ Wm,
    bf16* __restrict__ Wb, float4* __restrict__ Z)
{
    const int b = blockIdx.x, t = threadIdx.x;
    if (b < 66) {
        const int i = b * 256 + t;
        if (i < 16896) Z[i] = float4{0.f, 0.f, 0.f, 0.f};
        return;
    }
    const int wi = b - 66;              // 0..255
    const int m  = wi >> 6;             // matrix 0..3
    const float* S = (m == 0) ? Wq : (m == 1) ? Wk : (m == 2) ? Wv : Wm;
    const int idx = (wi & 63) * 1024 + t * 4;
    float4 v = *(const float4*)(S + idx);
    bf16x4 p = {(bf16)v.x, (bf16)v.y, (bf16)v.z, (bf16)v.w};
    *(bf16x4*)(Wb + (size_t)m * 65536 + idx) = p;
}

// ---------------------------------------------------------------------------
// Kernel A: fused K-proj + V-proj + KV aggregation for one (n, 32-row s-chunk).
// grid (128, 8), 256 threads (4 waves, each owns a 64-col slice).
// ---------------------------------------------------------------------------
__global__ __launch_bounds__(256, 2) void kv_fused(
    const float* __restrict__ kin, const float* __restrict__ vin,
    const bf16* __restrict__ Wkb, const bf16* __restrict__ Wvb,
    const float* __restrict__ bk, const float* __restrict__ bv,
    const int* __restrict__ kv_mask,
    float* __restrict__ KV, float* __restrict__ Ksum)
{
    const int n = blockIdx.y, s0 = blockIdx.x * 32;
    const int t = threadIdx.x, lane = t & 63, w = t >> 6;
    const int ln15 = lane & 15, lg = lane >> 4;
    const int wn = w * 64;

    __shared__ bf16 Xs[32][40];     // input tile (k-step), rows e-contig, 16B-aligned rows
    __shared__ bf16 Ws[256][40];    // W tile (k-step)
    __shared__ bf16 KfT[256][40];   // Kf transposed [c][s]
    __shared__ bf16 VmT[256][40];   // Vm transposed [c][s]

    const int xr = t >> 3, xc = (t & 7) * 4;   // X stage: 8 lanes x float4 per row
    const int wr = t >> 2, wc = (t & 3) * 8;   // W stage: 4 lanes x bf16x8 per row

    for (int g = 0; g < 2; ++g) {
        const float* X  = g ? vin : kin;
        const bf16*  Wg = g ? Wvb : Wkb;
        const float* bg = g ? bv : bk;
        f32x4 acc[2][4] = {};
        for (int k0 = 0; k0 < 256; k0 += 32) {
            float4 xv = *(const float4*)(X + ((size_t)(n * 4096 + s0 + xr)) * 256 + k0 + xc);
            bf16x4 xp = {(bf16)xv.x, (bf16)xv.y, (bf16)xv.z, (bf16)xv.w};
            *(bf16x4*)&Xs[xr][xc] = xp;
            #pragma unroll
            for (int i = 0; i < 4; ++i)
                *(bf16x8*)&Ws[wr + 64 * i][wc] =
                    *(const bf16x8*)(Wg + (size_t)(wr + 64 * i) * 256 + k0 + wc);
            __syncthreads();
            bf16x8 a[2], bfr[4];
            a[0] = *(const bf16x8*)&Xs[ln15][lg * 8];
            a[1] = *(const bf16x8*)&Xs[16 + ln15][lg * 8];
            #pragma unroll
            for (int ni = 0; ni < 4; ++ni)
                bfr[ni] = *(const bf16x8*)&Ws[wn + ni * 16 + ln15][lg * 8];
            #pragma unroll
            for (int mi = 0; mi < 2; ++mi)
                #pragma unroll
                for (int ni = 0; ni < 4; ++ni)
                    acc[mi][ni] = __builtin_amdgcn_mfma_f32_16x16x32_bf16(
                        a[mi], bfr[ni], acc[mi][ni], 0, 0, 0);
            __syncthreads();
        }
        // epilogue: bias (+elu+1 for Kf), mask, write transposed tile, Ksum reduce
        bf16 (*T)[40] = g ? VmT : KfT;
        #pragma unroll
        for (int ni = 0; ni < 4; ++ni) {
            const int col = wn + ni * 16 + ln15;
            const float bias = bg[col];
            float red = 0.f;
            #pragma unroll
            for (int mi = 0; mi < 2; ++mi) {
                const int sb = mi * 16 + lg * 4;
                bf16x4 pk;
                #pragma unroll
                for (int r = 0; r < 4; ++r) {
                    float x = acc[mi][ni][r] + bias;
                    if (g == 0) x = (x > 0.f) ? (x + 1.f) : __expf(x);
                    x *= kv_mask[n * 4096 + s0 + sb + r] ? 1.f : 0.f;
                    red += x;
                    pk[r] = (bf16)x;
                }
                *(bf16x4*)&T[col][sb] = pk;
            }
            if (g == 0) {
                red += __shfl_xor(red, 16);
                red += __shfl_xor(red, 32);
                if (lane < 16) atomicAdd(Ksum + n * 256 + col, red);
            }
        }
        __syncthreads();
    }
    // phase 2: KV^T[v][d] += sum_s Vm[s][v]*Kf[s][d]; wave w -> heads 2w, 2w+1
    #pragma unroll
    for (int hh = 0; hh < 2; ++hh) {
        const int h = w * 2 + hh;
        bf16x8 a[2], bb[2];
        #pragma unroll
        for (int mi = 0; mi < 2; ++mi)
            a[mi] = *(const bf16x8*)&VmT[h * 32 + mi * 16 + ln15][lg * 8];
        #pragma unroll
        for (int ni = 0; ni < 2; ++ni)
            bb[ni] = *(const bf16x8*)&KfT[h * 32 + ni * 16 + ln15][lg * 8];
        float* base = KV + (size_t)(n * 8 + h) * 1024;
        #pragma unroll
        for (int mi = 0; mi < 2; ++mi)
            #pragma unroll
            for (int ni = 0; ni < 2; ++ni) {
                f32x4 c = {};
                c = __builtin_amdgcn_mfma_f32_16x16x32_bf16(a[mi], bb[ni], c, 0, 0, 0);
                const int d = ni * 16 + ln15;
                #pragma unroll
                for (int r = 0; r < 4; ++r) {
                    const int v = mi * 16 + lg * 4 + r;
                    atomicAdd(base + v * 32 + d, c[r]);
                }
            }
    }
}

// ---------------------------------------------------------------------------
// Kernel B: fused Q-proj + linear-attention + merge GEMM for one (n, 32-row l-chunk).
// grid (128, 8), 256 threads.
// ---------------------------------------------------------------------------
__global__ __launch_bounds__(256, 2) void attn_fused(
    const float* __restrict__ qin, const bf16* __restrict__ Wqb,
    const float* __restrict__ bq, const int* __restrict__ q_mask,
    const bf16* __restrict__ Wmb,
    const float* __restrict__ KV, const float* __restrict__ Ksum,
    float* __restrict__ out)
{
    const int n = blockIdx.y, l0 = blockIdx.x * 32;
    const int t = threadIdx.x, lane = t & 63, w = t >> 6;
    const int ln15 = lane & 15, lg = lane >> 4;
    const int wn = w * 64;

    __shared__ bf16  Xs[32][40];
    __shared__ bf16  Ws[256][40];
    __shared__ bf16  Qs[32][264];     // Qf row-major [l][c]; later reused as Attn
    __shared__ bf16  KVs[8][32][40];  // KV^T [h][v][d]
    __shared__ float KSs[256];        // Ksum [h*32+d]
    __shared__ float Dens[32][8];

    // stage KV (fp32 -> bf16) and Ksum
    {
        const float* kvn = KV + (size_t)n * 8192;
        #pragma unroll
        for (int i = 0; i < 8; ++i) {
            const int idx = (t * 8 + i) * 4;          // 0..8188, step 4
            float4 vv = *(const float4*)(kvn + idx);
            bf16x4 p = {(bf16)vv.x, (bf16)vv.y, (bf16)vv.z, (bf16)vv.w};
            const int h = idx >> 10, rem = idx & 1023;
            *(bf16x4*)&KVs[h][rem >> 5][rem & 31] = p;
        }
        KSs[t] = Ksum[n * 256 + t];
    }
    // GEMM1: Qf = (elu(q@Wq^T + bq)+1) * q_mask  -> Qs[l][c]
    {
        const int xr = t >> 3, xc = (t & 7) * 4, wr = t >> 2, wc = (t & 3) * 8;
        f32x4 acc[2][4] = {};
        for (int k0 = 0; k0 < 256; k0 += 32) {
            float4 xv = *(const float4*)(qin + ((size_t)(n * 4096 + l0 + xr)) * 256 + k0 + xc);
            bf16x4 xp = {(bf16)xv.x, (bf16)xv.y, (bf16)xv.z, (bf16)xv.w};
            *(bf16x4*)&Xs[xr][xc] = xp;
            #pragma unroll
            for (int i = 0; i < 4; ++i)
                *(bf16x8*)&Ws[wr + 64 * i][wc] =
                    *(const bf16x8*)(Wqb + (size_t)(wr + 64 * i) * 256 + k0 + wc);
            __syncthreads();
            bf16x8 a[2], bfr[4];
            a[0] = *(const bf16x8*)&Xs[ln15][lg * 8];
            a[1] = *(const bf16x8*)&Xs[16 + ln15][lg * 8];
            #pragma unroll
            for (int ni = 0; ni < 4; ++ni)
                bfr[ni] = *(const bf16x8*)&Ws[wn + ni * 16 + ln15][lg * 8];
            #pragma unroll
            for (int mi = 0; mi < 2; ++mi)
                #pragma unroll
                for (int ni = 0; ni < 4; ++ni)
                    acc[mi][ni] = __builtin_amdgcn_mfma_f32_16x16x32_bf16(
                        a[mi], bfr[ni], acc[mi][ni], 0, 0, 0);
            __syncthreads();
        }
        #pragma unroll
        for (int ni = 0; ni < 4; ++ni) {
            const int col = wn + ni * 16 + ln15;
            const float bias = bq[col];
            #pragma unroll
            for (int mi = 0; mi < 2; ++mi)
                #pragma unroll
                for (int r = 0; r < 4; ++r) {
                    const int l = mi * 16 + lg * 4 + r;
                    float x = acc[mi][ni][r] + bias;
                    x = (x > 0.f) ? (x + 1.f) : __expf(x);
                    x *= q_mask[n * 4096 + l0 + l] ? 1.f : 0.f;
                    Qs[l][col] = (bf16)x;
                }
        }
    }
    __syncthreads();
    // den[l][h] = sum_d Qf[l][h*32+d] * Ksum[h][d]
    {
        const int l = t >> 3, h = t & 7;
        float s = 0.f;
        #pragma unroll
        for (int d = 0; d < 32; ++d)
            s += (float)Qs[l][h * 32 + d] * KSs[h * 32 + d];
        Dens[l][h] = s;
    }
    __syncthreads();
    // num^T[v][l] = sum_d KV^T[v][d] * Qf[l][d]; normalize; Attn overwrites Qs
    #pragma unroll
    for (int hh = 0; hh < 2; ++hh) {
        const int h = w * 2 + hh;
        bf16x8 a[2], bb[2];
        #pragma unroll
        for (int mi = 0; mi < 2; ++mi)
            a[mi] = *(const bf16x8*)&KVs[h][mi * 16 + ln15][lg * 8];
        #pragma unroll
        for (int ni = 0; ni < 2; ++ni)
            bb[ni] = *(const bf16x8*)&Qs[ni * 16 + ln15][h * 32 + lg * 8];
        f32x4 c[2][2];
        #pragma unroll
        for (int mi = 0; mi < 2; ++mi)
            #pragma unroll
            for (int ni = 0; ni < 2; ++ni) {
                f32x4 z = {};
                c[mi][ni] = __builtin_amdgcn_mfma_f32_16x16x32_bf16(a[mi], bb[ni], z, 0, 0, 0);
            }
        #pragma unroll
        for (int ni = 0; ni < 2; ++ni) {
            const int l = ni * 16 + ln15;
            const float rcp = 1.f / (Dens[l][h] + EPSF);
            #pragma unroll
            for (int mi = 0; mi < 2; ++mi) {
                bf16x4 pk;
                #pragma unroll
                for (int r = 0; r < 4; ++r) pk[r] = (bf16)(c[mi][ni][r] * rcp);
                *(bf16x4*)&Qs[l][h * 32 + mi * 16 + lg * 4] = pk;
            }
        }
    }
    __syncthreads();
    // GEMM2: out = Attn @ Wm^T (A-operand straight from LDS Qs)
    {
        const int wr = t >> 2, wc = (t & 3) * 8;
        f32x4 acc[2][4] = {};
        for (int k0 = 0; k0 < 256; k0 += 32) {
            #pragma unroll
            for (int i = 0; i < 4; ++i)
                *(bf16x8*)&Ws[wr + 64 * i][wc] =
                    *(const bf16x8*)(Wmb + (size_t)(wr + 64 * i) * 256 + k0 + wc);
            __syncthreads();
            bf16x8 a[2], bfr[4];
            a[0] = *(const bf16x8*)&Qs[ln15][k0 + lg * 8];
            a[1] = *(const bf16x8*)&Qs[16 + ln15][k0 + lg * 8];
            #pragma unroll
            for (int ni = 0; ni < 4; ++ni)
                bfr[ni] = *(const bf16x8*)&Ws[wn + ni * 16 + ln15][lg * 8];
            #pragma unroll
            for (int mi = 0; mi < 2; ++mi)
                #pragma unroll
                for (int ni = 0; ni < 4; ++ni)
                    acc[mi][ni] = __builtin_amdgcn_mfma_f32_16x16x32_bf16(
                        a[mi], bfr[ni], acc[mi][ni], 0, 0, 0);
            __syncthreads();
        }
        #pragma unroll
        for (int ni = 0; ni < 4; ++ni) {
            const int col = wn + ni * 16 + ln15;
            #pragma unroll
            for (int mi = 0; mi < 2; ++mi)
                #pragma unroll
                for (int r = 0; r < 4; ++r) {
                    const int l = mi * 16 + lg * 4 + r;
                    out[((size_t)(n * 4096 + l0 + l)) * 256 + col] = acc[mi][ni][r];
                }
        }
    }
}

extern "C" void kernel_launch(void* const* d_in, const int* in_sizes, int n_in,
                              void* d_out, int out_size, void* d_ws, size_t ws_size,
                              hipStream_t stream) {
    const float* q      = (const float*)d_in[0];
    const float* k      = (const float*)d_in[1];
    const float* v      = (const float*)d_in[2];
    const int*   q_mask = (const int*)  d_in[3];
    const int*   kv_mask= (const int*)  d_in[4];
    const float* Wq     = (const float*)d_in[5];
    const float* bq     = (const float*)d_in[6];
    const float* Wk     = (const float*)d_in[7];
    const float* bk     = (const float*)d_in[8];
    const float* Wv     = (const float*)d_in[9];
    const float* bv     = (const float*)d_in[10];
    const float* Wm     = (const float*)d_in[11];

    char* ws = (char*)d_ws;
    float* KV   = (float*)ws;                         // 65536 f32
    float* Ksum = (float*)(ws + 262144);              // 2048 f32
    bf16*  Wb   = (bf16*)(ws + 270336);               // 4 x 65536 bf16
    bf16*  Wqb = Wb, *Wkb = Wb + 65536, *Wvb = Wb + 131072, *Wmb = Wb + 196608;

    const dim3 blk(256);
    prep<<<dim3(322), blk, 0, stream>>>(Wq, Wk, Wv, Wm, Wb, (float4*)ws);
    kv_fused<<<dim3(128, 8), blk, 0, stream>>>(k, v, Wkb, Wvb, bk, bv, kv_mask, KV, Ksum);
    attn_fused<<<dim3(128, 8), blk, 0, stream>>>(q, Wqb, bq, q_mask, Wmb, KV, Ksum, (float*)d_out);
}